// Round 16
// baseline (446.331 us; speedup 1.0000x reference)
//
#include <hip/hip_runtime.h>
#include <hip/hip_cooperative_groups.h>

namespace cg = cooperative_groups;

#define D 32
#define BSZ 131                 // nodes per bucket -> Bn = 764
#define PN BSZ
#define CAP 2816                // per-bucket record capacity
#define APL 17                  // u64 stride of atomic accumulators
#define WP 36                   // weight row stride
#define SF 36                   // sfeat/sacc row stride
#define DEPTH 12                // stream depth, f32 fallback
#define DEPTHH 16               // stream depth, bf16 path

#define FXS2 32768.0f
#define FXINV2 3.0517578125e-05f
#define OFF 8.0f
#define DEGBIAS 262144u

// fallback pass-1 config (r13-proven)
#define TILEF 4096
#define TMAXF 512
#define BMAXF 1024
#define STHREADS 1024

__device__ __forceinline__ unsigned short f2bf(float x) {
    unsigned u = __float_as_uint(x);
    unsigned r = (u + 0x7FFF + ((u >> 16) & 1)) >> 16;   // RNE
    return (unsigned short)r;
}
__device__ __forceinline__ float bf2f(unsigned short h) {
    return __uint_as_float((unsigned)h << 16);
}
__device__ __forceinline__ unsigned enc(float x) {
    return __float2uint_rn((x + OFF) * FXS2);
}

// ================= Fused cooperative kernel (tile b -> grid sync -> bucket b) ============
template <bool USEH>
__global__ __launch_bounds__(512, 6) void sage_fused(
        const int* __restrict__ src, const int* __restrict__ dst,
        int* __restrict__ records, unsigned short* __restrict__ startsT,
        const float* __restrict__ feat, unsigned short* __restrict__ featH,
        const float* __restrict__ Wself, const float* __restrict__ Wneigh,
        const float* __restrict__ bias, float* __restrict__ out,
        int N, int E, int T, int tile2) {
    __shared__ float ubuf[(PN + 1) * SF];
    __shared__ unsigned long long sacc8[((PN + 1) * SF) / 2];
    __shared__ float sWs[D * WP];
    __shared__ float sWn[D * WP];
    __shared__ float sb[D];
    __shared__ int sdeg[PN + 1];
    __shared__ unsigned short tstart16[768];
    __shared__ unsigned short tbase16[768];
    __shared__ int wsum2[8];
    __shared__ int ctot;

    int t = threadIdx.x;
    int lane = t & 63;
    int wid = t >> 6;
    int bid = blockIdx.x;

    // ---------- Phase S: scatter tile 'bid' ----------
    int* stage = reinterpret_cast<int*>(ubuf);
    int* lhist = reinterpret_cast<int*>(sacc8);
    int* lofs  = reinterpret_cast<int*>(sacc8) + 768;

    for (int i = t; i <= T; i += 512) lhist[i] = 0;
    __syncthreads();

    int tileStart = bid * tile2;
    int cntTile = min(E - tileStart, tile2);

    int recs[5], bks[5], rr[5];
#pragma unroll
    for (int i = 0; i < 5; ++i) {
        int idx = t + i * 512;
        bks[i] = -1;
        if (idx < cntTile) {
            int e = tileStart + idx;
            int s = src[e], d = dst[e];
            int b = (int)((unsigned)d / (unsigned)BSZ);
            int nl = d - b * BSZ;
            recs[i] = (s << 8) | nl;
            bks[i] = b;
            rr[i] = atomicAdd(&lhist[b], 1);
        }
    }
    __syncthreads();

    int mb = 0;
    for (int chunk = 0; chunk <= T; chunk += 512) {
        int tt = chunk + t;
        int own = (tt <= T) ? lhist[tt] : 0;
        int v = own;
#pragma unroll
        for (int off = 1; off < 64; off <<= 1) {
            int u = __shfl_up(v, off, 64);
            if (lane >= off) v += u;
        }
        if (lane == 63) wsum2[wid] = v;
        __syncthreads();
        if (wid == 0) {
            int s = (lane < 8) ? wsum2[lane] : 0;
#pragma unroll
            for (int off = 1; off < 8; off <<= 1) {
                int u = __shfl_up(s, off, 64);
                if (lane >= off) s += u;
            }
            if (lane < 8) wsum2[lane] = s;
        }
        __syncthreads();
        int incl = v + (wid ? wsum2[wid - 1] : 0);
        int ex = mb + incl - own;
        if (tt <= T) {
            startsT[(size_t)tt * T + bid] = (unsigned short)ex;
            if (tt < T) lofs[tt] = ex;
        }
        if (t == 511) ctot = incl;
        __syncthreads();
        mb += ctot;
    }

#pragma unroll
    for (int i = 0; i < 5; ++i)
        if (bks[i] >= 0) stage[lofs[bks[i]] + rr[i]] = recs[i];
    __syncthreads();

    for (int i = t; i < cntTile; i += 512)
        records[(size_t)bid * tile2 + i] = stage[i];

    if (USEH) {
        int total4 = (N * D) >> 2;
        for (int i = bid * 512 + t; i < total4; i += gridDim.x * 512) {
            float4 f = ((const float4*)feat)[i];
            ushort4 h;
            h.x = f2bf(f.x); h.y = f2bf(f.y); h.z = f2bf(f.z); h.w = f2bf(f.w);
            ((ushort4*)featH)[i] = h;
        }
    }

    __threadfence();
    cg::this_grid().sync();
    __threadfence();   // acquire side (cross-XCD safety)

    // ---------- Phase G: bucket 'bid' ----------
    int b = bid;
    int* raw = reinterpret_cast<int*>(ubuf);
    float* sfeatF = ubuf;
    float* saccF = reinterpret_cast<float*>(sacc8);

    const int NSLOT = PN * 8;
    float4 fr[3];
#pragma unroll
    for (int u = 0; u < 3; ++u) fr[u] = make_float4(0.f, 0.f, 0.f, 0.f);
#pragma unroll
    for (int u = 0; u < 3; ++u) {
        int idx = t + 512 * u;
        if (idx < NSLOT) {
            int n = b * BSZ + (idx >> 3);
            if (n < N) fr[u] = ((const float4*)feat)[(size_t)n * 8 + (idx & 7)];
        }
    }

    for (int i = t; i < ((PN + 1) * SF) / 2; i += 512) sacc8[i] = 0ull;
    if (t <= PN) sdeg[t] = 0;
    for (int i = t; i < D * D; i += 512) {
        int r = i >> 5, c = i & 31;
        sWs[r * WP + c] = Wself[i];
        sWn[r * WP + c] = Wneigh[i];
    }
    if (t < D) sb[t] = bias[t];

    int mb2 = 0;
    for (int chunk = 0; chunk < T; chunk += 512) {
        int tt = chunk + t;
        int myc = 0;
        if (tt < T) {
            int s0v = startsT[(size_t)b * T + tt];
            int s1v = startsT[(size_t)(b + 1) * T + tt];
            tstart16[tt] = (unsigned short)s0v;
            myc = s1v - s0v;
        }
        int v = myc;
#pragma unroll
        for (int off = 1; off < 64; off <<= 1) {
            int u = __shfl_up(v, off, 64);
            if (lane >= off) v += u;
        }
        if (lane == 63) wsum2[wid] = v;
        __syncthreads();
        if (wid == 0) {
            int s = (lane < 8) ? wsum2[lane] : 0;
#pragma unroll
            for (int off = 1; off < 8; off <<= 1) {
                int u = __shfl_up(s, off, 64);
                if (lane >= off) s += u;
            }
            if (lane < 8) wsum2[lane] = s;
        }
        __syncthreads();
        int incl = v + (wid ? wsum2[wid - 1] : 0);
        if (tt < T) tbase16[tt] = (unsigned short)(mb2 + incl - myc);
        if (t == 511) ctot = incl;
        __syncthreads();
        mb2 += ctot;
    }
    if (t == 0) tbase16[T] = (unsigned short)mb2;
    __syncthreads();

    int m = min(mb2, CAP);

    int lane4 = t & 3, tg4 = t >> 2;
    for (int tau = tg4; tau < T; tau += 128) {
        int s = tstart16[tau];
        int rb = tbase16[tau];
        int c2 = (int)tbase16[tau + 1] - rb;
        const int* rp = records + (size_t)tau * tile2 + s;
        for (int l = lane4; l < c2; l += 4) {
            int pos = rb + l;
            if (pos < CAP) raw[pos] = rp[l];
        }
    }
    __syncthreads();

    int team = t >> 3;
    int part = t & 7;
    if (USEH) {
        for (int base = team; base < m; base += 64 * DEPTHH) {
            ushort4 hv[DEPTHH];
            int nl8[DEPTHH];
            bool ok[DEPTHH];
#pragma unroll
            for (int u = 0; u < DEPTHH; ++u) {
                int idx = base + 64 * u;
                ok[u] = idx < m;
                int rec = raw[ok[u] ? idx : 0];
                int s = rec >> 8;
                nl8[u] = rec & 255;
                hv[u] = *reinterpret_cast<const ushort4*>(
                    featH + (size_t)s * D + part * 4);
            }
#pragma unroll
            for (int u = 0; u < DEPTHH; ++u) {
                if (ok[u]) {
                    unsigned long long* ac = &sacc8[nl8[u] * APL + part * 2];
                    unsigned a0 = enc(bf2f(hv[u].x));
                    unsigned a1 = enc(bf2f(hv[u].y));
                    unsigned a2 = enc(bf2f(hv[u].z));
                    unsigned a3 = enc(bf2f(hv[u].w));
                    atomicAdd(ac + 0, (unsigned long long)a0 | ((unsigned long long)a1 << 32));
                    atomicAdd(ac + 1, (unsigned long long)a2 | ((unsigned long long)a3 << 32));
                    if (part == 0) atomicAdd(&sdeg[nl8[u]], 1);
                }
            }
        }
    } else {
        for (int base = team; base < m; base += 64 * DEPTH) {
            float4 vv[DEPTH];
            int nl8[DEPTH];
            bool ok[DEPTH];
#pragma unroll
            for (int u = 0; u < DEPTH; ++u) {
                int idx = base + 64 * u;
                ok[u] = idx < m;
                int rec = raw[ok[u] ? idx : 0];
                int s = rec >> 8;
                nl8[u] = rec & 255;
                vv[u] = *reinterpret_cast<const float4*>(
                    feat + (size_t)s * D + part * 4);
            }
#pragma unroll
            for (int u = 0; u < DEPTH; ++u) {
                if (ok[u]) {
                    unsigned long long* ac = &sacc8[nl8[u] * APL + part * 2];
                    unsigned a0 = enc(vv[u].x);
                    unsigned a1 = enc(vv[u].y);
                    unsigned a2 = enc(vv[u].z);
                    unsigned a3 = enc(vv[u].w);
                    atomicAdd(ac + 0, (unsigned long long)a0 | ((unsigned long long)a1 << 32));
                    atomicAdd(ac + 1, (unsigned long long)a2 | ((unsigned long long)a3 << 32));
                    if (part == 0) atomicAdd(&sdeg[nl8[u]], 1);
                }
            }
        }
    }
    __syncthreads();

    unsigned rv[9];
    const unsigned* sview = reinterpret_cast<const unsigned*>(sacc8);
#pragma unroll
    for (int r = 0; r < 9; ++r) {
        int i = t + 512 * r;
        if (i < PN * 32) rv[r] = sview[(i >> 5) * (2 * APL) + (i & 31)];
    }
    __syncthreads();
#pragma unroll
    for (int r = 0; r < 9; ++r) {
        int i = t + 512 * r;
        if (i < PN * 32) {
            int node = i >> 5, col = i & 31;
            int iv = (int)(rv[r] - (unsigned)sdeg[node] * DEGBIAS);
            saccF[node * SF + col] = (float)iv * FXINV2;
        }
    }
#pragma unroll
    for (int u = 0; u < 3; ++u) {
        int idx = t + 512 * u;
        if (idx < NSLOT)
            *reinterpret_cast<float4*>(&sfeatF[(idx >> 3) * SF + (idx & 7) * 4]) = fr[u];
    }
    __syncthreads();

    int jp = t & 15;
    int nq = t >> 4;
    int j0 = jp, j1 = jp + 16;
    float b0 = sb[j0], b1 = sb[j1];
    for (int p2 = 0; p2 < 2; ++p2) {
        int q0 = nq + 32 * p2;
        if (q0 * 4 >= PN) break;
        float accS[4][2], accN[4][2];
#pragma unroll
        for (int i = 0; i < 4; ++i) {
            accS[i][0] = 0.f; accS[i][1] = 0.f;
            accN[i][0] = 0.f; accN[i][1] = 0.f;
        }
        const float* fb = &sfeatF[(q0 * 4) * SF];
        const float* nb = &saccF[(q0 * 4) * SF];
#pragma unroll 1
        for (int kk = 0; kk < 8; ++kk) {
            float4 w0 = *reinterpret_cast<const float4*>(&sWs[j0 * WP + kk * 4]);
            float4 w1 = *reinterpret_cast<const float4*>(&sWs[j1 * WP + kk * 4]);
            float4 u0 = *reinterpret_cast<const float4*>(&sWn[j0 * WP + kk * 4]);
            float4 u1 = *reinterpret_cast<const float4*>(&sWn[j1 * WP + kk * 4]);
#pragma unroll
            for (int i = 0; i < 4; ++i) {
                float4 f4 = *reinterpret_cast<const float4*>(&fb[i * SF + kk * 4]);
                float4 n4 = *reinterpret_cast<const float4*>(&nb[i * SF + kk * 4]);
                accS[i][0] += f4.x * w0.x + f4.y * w0.y + f4.z * w0.z + f4.w * w0.w;
                accS[i][1] += f4.x * w1.x + f4.y * w1.y + f4.z * w1.z + f4.w * w1.w;
                accN[i][0] += n4.x * u0.x + n4.y * u0.y + n4.z * u0.z + n4.w * u0.w;
                accN[i][1] += n4.x * u1.x + n4.y * u1.y + n4.z * u1.z + n4.w * u1.w;
            }
        }
#pragma unroll
        for (int i = 0; i < 4; ++i) {
            int nl = q0 * 4 + i;
            int n = b * BSZ + nl;
            if (nl < PN && n < N) {
                float inv = 1.0f / (float)max(sdeg[nl], 1);
                out[(size_t)n * D + j0] = accS[i][0] + inv * accN[i][0] + b0;
                out[(size_t)n * D + j1] = accS[i][1] + inv * accN[i][1] + b1;
            }
        }
    }
}

// ================= Fallback path: r13-proven two-kernel pipeline =================
__global__ __launch_bounds__(STHREADS) void scatter_tiles_fb(
        const int* __restrict__ src, const int* __restrict__ dst,
        int* __restrict__ records, int* __restrict__ startsT,
        const float* __restrict__ feat, unsigned short* __restrict__ featH,
        int E, int Bn, int T, int N, int useH) {
    __shared__ int lhist[STHREADS];
    __shared__ int lofs[BMAXF];
    __shared__ int wsum[16];
    __shared__ int stage[TILEF];

    int t = threadIdx.x;
    int lane = t & 63;
    int wid = t >> 6;
    int tileStart = blockIdx.x * TILEF;

    lhist[t] = 0;
    __syncthreads();

    int sarr[4], darr[4];
    int e0 = tileStart + 4 * t;
    if (tileStart + TILEF <= E) {
        int4 s4 = ((const int4*)src)[tileStart / 4 + t];
        int4 d4 = ((const int4*)dst)[tileStart / 4 + t];
        sarr[0] = s4.x; sarr[1] = s4.y; sarr[2] = s4.z; sarr[3] = s4.w;
        darr[0] = d4.x; darr[1] = d4.y; darr[2] = d4.z; darr[3] = d4.w;
    } else {
#pragma unroll
        for (int i = 0; i < 4; ++i) {
            int e = e0 + i;
            sarr[i] = (e < E) ? src[e] : 0;
            darr[i] = (e < E) ? dst[e] : 0;
        }
    }

    int recs[4], bks[4], rr[4];
#pragma unroll
    for (int i = 0; i < 4; ++i) {
        int e = e0 + i;
        if (e < E) {
            int b = (int)((unsigned)darr[i] / (unsigned)BSZ);
            int nl = darr[i] - b * BSZ;
            recs[i] = (sarr[i] << 8) | nl;
            bks[i] = b;
            rr[i] = atomicAdd(&lhist[b], 1);
        } else bks[i] = -1;
    }
    __syncthreads();

    int own = lhist[t];
    int v = own;
#pragma unroll
    for (int off = 1; off < 64; off <<= 1) {
        int u = __shfl_up(v, off, 64);
        if (lane >= off) v += u;
    }
    if (lane == 63) wsum[wid] = v;
    __syncthreads();
    if (wid == 0) {
        int s = (lane < 16) ? wsum[lane] : 0;
#pragma unroll
        for (int off = 1; off < 16; off <<= 1) {
            int u = __shfl_up(s, off, 64);
            if (lane >= off) s += u;
        }
        if (lane < 16) wsum[lane] = s;
    }
    __syncthreads();
    int incl = v + (wid ? wsum[wid - 1] : 0);
    int ex = incl - own;
    if (t <= Bn) startsT[(size_t)t * T + blockIdx.x] = ex;
    if (t < Bn) lofs[t] = ex;
    __syncthreads();

#pragma unroll
    for (int i = 0; i < 4; ++i) {
        if (bks[i] >= 0) stage[lofs[bks[i]] + rr[i]] = recs[i];
    }
    __syncthreads();

    int4* dp = reinterpret_cast<int4*>(records + (size_t)tileStart);
    const int4* sp = reinterpret_cast<const int4*>(stage);
    dp[t] = sp[t];

    if (useH) {
        int total4 = (N * D) >> 2;
        for (int i = blockIdx.x * STHREADS + t; i < total4; i += gridDim.x * STHREADS) {
            float4 f = ((const float4*)feat)[i];
            ushort4 h;
            h.x = f2bf(f.x); h.y = f2bf(f.y); h.z = f2bf(f.z); h.w = f2bf(f.w);
            ((ushort4*)featH)[i] = h;
        }
    }
}

template <bool USEH>
__global__ __launch_bounds__(512) void bucket_final_fb(
        const float* __restrict__ feat, const unsigned short* __restrict__ featH,
        const int* __restrict__ records, const int* __restrict__ startsT,
        const float* __restrict__ Wself, const float* __restrict__ Wneigh,
        const float* __restrict__ bias, float* __restrict__ out,
        int N, int T, int Bn) {
    __shared__ float ubuf[(PN + 1) * SF];
    __shared__ unsigned long long sacc8[((PN + 1) * SF) / 2];
    __shared__ float sWs[D * WP];
    __shared__ float sWn[D * WP];
    __shared__ float sb[D];
    __shared__ int sdeg[PN + 1];
    __shared__ int tstart[TMAXF];
    __shared__ int tbase[TMAXF + 1];
    __shared__ int wsum2[8];

    int* raw = reinterpret_cast<int*>(ubuf);
    float* sfeatF = ubuf;
    float* saccF = reinterpret_cast<float*>(sacc8);

    int b = blockIdx.x;
    int t = threadIdx.x;
    int lane = t & 63;
    int wid = t >> 6;

    const int NSLOT = PN * 8;
    float4 fr[3];
#pragma unroll
    for (int u = 0; u < 3; ++u) fr[u] = make_float4(0.f, 0.f, 0.f, 0.f);
#pragma unroll
    for (int u = 0; u < 3; ++u) {
        int idx = t + 512 * u;
        if (idx < NSLOT) {
            int n = b * BSZ + (idx >> 3);
            if (n < N) fr[u] = ((const float4*)feat)[(size_t)n * 8 + (idx & 7)];
        }
    }

    for (int i = t; i < ((PN + 1) * SF) / 2; i += 512) sacc8[i] = 0ull;
    if (t <= PN) sdeg[t] = 0;
    for (int i = t; i < D * D; i += 512) {
        int r = i >> 5, c = i & 31;
        sWs[r * WP + c] = Wself[i];
        sWn[r * WP + c] = Wneigh[i];
    }
    if (t < D) sb[t] = bias[t];

    int myc = 0;
    if (t < T) {
        int s0v = startsT[(size_t)b * T + t];
        int s1v = startsT[(size_t)(b + 1) * T + t];
        tstart[t] = s0v;
        myc = s1v - s0v;
    }
    int v = myc;
#pragma unroll
    for (int off = 1; off < 64; off <<= 1) {
        int u = __shfl_up(v, off, 64);
        if (lane >= off) v += u;
    }
    if (lane == 63) wsum2[wid] = v;
    __syncthreads();
    if (wid == 0) {
        int s = (lane < 8) ? wsum2[lane] : 0;
#pragma unroll
        for (int off = 1; off < 8; off <<= 1) {
            int u = __shfl_up(s, off, 64);
            if (lane >= off) s += u;
        }
        if (lane < 8) wsum2[lane] = s;
    }
    __syncthreads();
    int incl = v + (wid ? wsum2[wid - 1] : 0);
    if (t < T) tbase[t] = incl - myc;
    if (t == T - 1) tbase[T] = incl;
    __syncthreads();

    int m = min(tbase[T], CAP);

    int lane4 = t & 3, tg4 = t >> 2;
    for (int tau = tg4; tau < T; tau += 128) {
        int s = tstart[tau];
        int rb = tbase[tau];
        int c2 = tbase[tau + 1] - rb;
        const int* rp = records + (size_t)tau * TILEF + s;
        for (int l = lane4; l < c2; l += 4) {
            int pos = rb + l;
            if (pos < CAP) raw[pos] = rp[l];
        }
    }
    __syncthreads();

    int team = t >> 3;
    int part = t & 7;
    if (USEH) {
        for (int base = team; base < m; base += 64 * DEPTHH) {
            ushort4 hv[DEPTHH];
            int nl8[DEPTHH];
            bool ok[DEPTHH];
#pragma unroll
            for (int u = 0; u < DEPTHH; ++u) {
                int idx = base + 64 * u;
                ok[u] = idx < m;
                int rec = raw[ok[u] ? idx : 0];
                int s = rec >> 8;
                nl8[u] = rec & 255;
                hv[u] = *reinterpret_cast<const ushort4*>(
                    featH + (size_t)s * D + part * 4);
            }
#pragma unroll
            for (int u = 0; u < DEPTHH; ++u) {
                if (ok[u]) {
                    unsigned long long* ac = &sacc8[nl8[u] * APL + part * 2];
                    unsigned a0 = enc(bf2f(hv[u].x));
                    unsigned a1 = enc(bf2f(hv[u].y));
                    unsigned a2 = enc(bf2f(hv[u].z));
                    unsigned a3 = enc(bf2f(hv[u].w));
                    atomicAdd(ac + 0, (unsigned long long)a0 | ((unsigned long long)a1 << 32));
                    atomicAdd(ac + 1, (unsigned long long)a2 | ((unsigned long long)a3 << 32));
                    if (part == 0) atomicAdd(&sdeg[nl8[u]], 1);
                }
            }
        }
    } else {
        for (int base = team; base < m; base += 64 * DEPTH) {
            float4 vv[DEPTH];
            int nl8[DEPTH];
            bool ok[DEPTH];
#pragma unroll
            for (int u = 0; u < DEPTH; ++u) {
                int idx = base + 64 * u;
                ok[u] = idx < m;
                int rec = raw[ok[u] ? idx : 0];
                int s = rec >> 8;
                nl8[u] = rec & 255;
                vv[u] = *reinterpret_cast<const float4*>(
                    feat + (size_t)s * D + part * 4);
            }
#pragma unroll
            for (int u = 0; u < DEPTH; ++u) {
                if (ok[u]) {
                    unsigned long long* ac = &sacc8[nl8[u] * APL + part * 2];
                    unsigned a0 = enc(vv[u].x);
                    unsigned a1 = enc(vv[u].y);
                    unsigned a2 = enc(vv[u].z);
                    unsigned a3 = enc(vv[u].w);
                    atomicAdd(ac + 0, (unsigned long long)a0 | ((unsigned long long)a1 << 32));
                    atomicAdd(ac + 1, (unsigned long long)a2 | ((unsigned long long)a3 << 32));
                    if (part == 0) atomicAdd(&sdeg[nl8[u]], 1);
                }
            }
        }
    }
    __syncthreads();

    unsigned rv[9];
    const unsigned* sview = reinterpret_cast<const unsigned*>(sacc8);
#pragma unroll
    for (int r = 0; r < 9; ++r) {
        int i = t + 512 * r;
        if (i < PN * 32) rv[r] = sview[(i >> 5) * (2 * APL) + (i & 31)];
    }
    __syncthreads();
#pragma unroll
    for (int r = 0; r < 9; ++r) {
        int i = t + 512 * r;
        if (i < PN * 32) {
            int node = i >> 5, col = i & 31;
            int iv = (int)(rv[r] - (unsigned)sdeg[node] * DEGBIAS);
            saccF[node * SF + col] = (float)iv * FXINV2;
        }
    }
#pragma unroll
    for (int u = 0; u < 3; ++u) {
        int idx = t + 512 * u;
        if (idx < NSLOT)
            *reinterpret_cast<float4*>(&sfeatF[(idx >> 3) * SF + (idx & 7) * 4]) = fr[u];
    }
    __syncthreads();

    int jp = t & 15;
    int nq = t >> 4;
    int j0 = jp, j1 = jp + 16;
    float b0 = sb[j0], b1 = sb[j1];
    for (int p2 = 0; p2 < 2; ++p2) {
        int q0 = nq + 32 * p2;
        if (q0 * 4 >= PN) break;
        float accS[4][2], accN[4][2];
#pragma unroll
        for (int i = 0; i < 4; ++i) {
            accS[i][0] = 0.f; accS[i][1] = 0.f;
            accN[i][0] = 0.f; accN[i][1] = 0.f;
        }
        const float* fb = &sfeatF[(q0 * 4) * SF];
        const float* nb = &saccF[(q0 * 4) * SF];
#pragma unroll 1
        for (int kk = 0; kk < 8; ++kk) {
            float4 w0 = *reinterpret_cast<const float4*>(&sWs[j0 * WP + kk * 4]);
            float4 w1 = *reinterpret_cast<const float4*>(&sWs[j1 * WP + kk * 4]);
            float4 u0 = *reinterpret_cast<const float4*>(&sWn[j0 * WP + kk * 4]);
            float4 u1 = *reinterpret_cast<const float4*>(&sWn[j1 * WP + kk * 4]);
#pragma unroll
            for (int i = 0; i < 4; ++i) {
                float4 f4 = *reinterpret_cast<const float4*>(&fb[i * SF + kk * 4]);
                float4 n4 = *reinterpret_cast<const float4*>(&nb[i * SF + kk * 4]);
                accS[i][0] += f4.x * w0.x + f4.y * w0.y + f4.z * w0.z + f4.w * w0.w;
                accS[i][1] += f4.x * w1.x + f4.y * w1.y + f4.z * w1.z + f4.w * w1.w;
                accN[i][0] += n4.x * u0.x + n4.y * u0.y + n4.z * u0.z + n4.w * u0.w;
                accN[i][1] += n4.x * u1.x + n4.y * u1.y + n4.z * u1.z + n4.w * u1.w;
            }
        }
#pragma unroll
        for (int i = 0; i < 4; ++i) {
            int nl = q0 * 4 + i;
            int n = b * BSZ + nl;
            if (nl < PN && n < N) {
                float inv = 1.0f / (float)max(sdeg[nl], 1);
                out[(size_t)n * D + j0] = accS[i][0] + inv * accN[i][0] + b0;
                out[(size_t)n * D + j1] = accS[i][1] + inv * accN[i][1] + b1;
            }
        }
    }
}

extern "C" void kernel_launch(void* const* d_in, const int* in_sizes, int n_in,
                              void* d_out, int out_size, void* d_ws, size_t ws_size,
                              hipStream_t stream) {
    const float* feat   = (const float*)d_in[0];
    const float* Wself  = (const float*)d_in[1];
    const float* Wneigh = (const float*)d_in[2];
    const float* bnb    = (const float*)d_in[3];
    const int*   src    = (const int*)d_in[4];
    const int*   dst    = (const int*)d_in[5];
    float* outp = (float*)d_out;

    int N = in_sizes[0] / D;            // 100000
    int E = in_sizes[4];                // 1600000
    int Bn = (N + BSZ - 1) / BSZ;       // 764

    // ---- fused layout ----
    int Tc = Bn;                        // 764 tiles/buckets
    int tile2 = (E + Tc - 1) / Tc;      // 2095
    size_t recBc = (size_t)Tc * tile2 * sizeof(int);
    size_t stBc  = (size_t)(Tc + 1) * Tc * sizeof(unsigned short);
    size_t fhOffc = (recBc + stBc + 63) & ~(size_t)63;
    size_t fhB = (size_t)N * D * sizeof(unsigned short);
    int useHc = (fhOffc + fhB <= ws_size) ? 1 : 0;

    int* recordsC = (int*)d_ws;
    unsigned short* startsTC = (unsigned short*)((char*)d_ws + recBc);
    unsigned short* featHC = (unsigned short*)((char*)d_ws + fhOffc);

    void* args[] = {(void*)&src, (void*)&dst, (void*)&recordsC, (void*)&startsTC,
                    (void*)&feat, (void*)&featHC, (void*)&Wself, (void*)&Wneigh,
                    (void*)&bnb, (void*)&outp, (void*)&N, (void*)&E, (void*)&Tc,
                    (void*)&tile2};

    hipError_t err;
    if (useHc)
        err = hipLaunchCooperativeKernel(
            reinterpret_cast<const void*>(&sage_fused<true>),
            dim3(Tc), dim3(512), args, 0, stream);
    else
        err = hipLaunchCooperativeKernel(
            reinterpret_cast<const void*>(&sage_fused<false>),
            dim3(Tc), dim3(512), args, 0, stream);

    if (err != hipSuccess) {
        // ---- fallback: r13-proven two-kernel path ----
        int T = (E + TILEF - 1) / TILEF;    // 391
        size_t recB = (size_t)T * TILEF * sizeof(int);
        size_t stB  = (size_t)(Bn + 1) * T * sizeof(int);
        size_t fhOff = (recB + stB + 63) & ~(size_t)63;
        int useH = (fhOff + fhB <= ws_size) ? 1 : 0;

        int* records = (int*)d_ws;
        int* startsT = (int*)((char*)d_ws + recB);
        unsigned short* featH = (unsigned short*)((char*)d_ws + fhOff);

        scatter_tiles_fb<<<T, STHREADS, 0, stream>>>(src, dst, records, startsT,
                                                     feat, featH, E, Bn, T, N, useH);
        if (useH)
            bucket_final_fb<true><<<Bn, 512, 0, stream>>>(feat, featH, records, startsT,
                                                          Wself, Wneigh, bnb, outp, N, T, Bn);
        else
            bucket_final_fb<false><<<Bn, 512, 0, stream>>>(feat, featH, records, startsT,
                                                           Wself, Wneigh, bnb, outp, N, T, Bn);
    }
}

// Round 17
// 127.763 us; speedup vs baseline: 3.4934x; 3.4934x over previous
//
#include <hip/hip_runtime.h>

#define D 32
#define BSZ 131                 // nodes per bucket (non-pow2 -> Bn=764)
#define PN BSZ
#define BMAX 1024               // scan width (Bn=764 fits)
#define TILE 4096               // edges per pass-1 tile
#define STHREADS 1024
#define CAP 2816                // per-bucket record capacity (mean m ~2094, +10 sigma)
#define TMAX 512                // max tiles (E=1.6M -> 391)
#define APL 17                  // u64 stride of atomic accumulators (odd -> bank spread)
#define WP 36                   // weight row stride (16B-aligned for float4 reads)
#define SF 36                   // sfeat/sacc-float row stride (16B-aligned, 2-way banks)
#define DEPTH 12                // phase-C records in flight (f32 fallback path)
#define DEPTHH 16               // phase-C records in flight (bf16 path)

#define FXS2 32768.0f           // 2^15 fixed-point scale
#define FXINV2 3.0517578125e-05f
#define OFF 8.0f                // positivity bias
#define DEGBIAS 262144u         // OFF * FXS2

__device__ __forceinline__ unsigned short f2bf(float x) {
    unsigned u = __float_as_uint(x);
    unsigned r = (u + 0x7FFF + ((u >> 16) & 1)) >> 16;   // round-to-nearest-even
    return (unsigned short)r;
}
__device__ __forceinline__ float bf2f(unsigned short h) {
    return __uint_as_float((unsigned)h << 16);
}
__device__ __forceinline__ unsigned enc(float x) {
    return __float2uint_rn((x + OFF) * FXS2);
}

// ---------- Pass 1: per-tile counting sort (rank fused with histogram atomic),
//            staged LDS sort + coalesced int4 flush, transposed starts write,
//            plus grid-stride feat -> bf16 shadow conversion ----------
__global__ __launch_bounds__(STHREADS) void scatter_tiles(
        const int* __restrict__ src, const int* __restrict__ dst,
        int* __restrict__ records, int* __restrict__ startsT,
        const float* __restrict__ feat, unsigned short* __restrict__ featH,
        int E, int Bn, int T, int N, int useH) {
    __shared__ int lhist[STHREADS];
    __shared__ int lofs[BMAX];
    __shared__ int wsum[16];
    __shared__ int stage[TILE];

    int t = threadIdx.x;
    int lane = t & 63;
    int wid = t >> 6;
    int tileStart = blockIdx.x * TILE;

    lhist[t] = 0;
    __syncthreads();

    // edge load: vectorized int4 except for the (partial) last tile
    int sarr[4], darr[4];
    int e0 = tileStart + 4 * t;
    if (tileStart + TILE <= E) {
        int4 s4 = ((const int4*)src)[tileStart / 4 + t];
        int4 d4 = ((const int4*)dst)[tileStart / 4 + t];
        sarr[0] = s4.x; sarr[1] = s4.y; sarr[2] = s4.z; sarr[3] = s4.w;
        darr[0] = d4.x; darr[1] = d4.y; darr[2] = d4.z; darr[3] = d4.w;
    } else {
#pragma unroll
        for (int i = 0; i < 4; ++i) {
            int e = e0 + i;
            sarr[i] = (e < E) ? src[e] : 0;
            darr[i] = (e < E) ? dst[e] : 0;
        }
    }

    int recs[4], bks[4], rr[4];
#pragma unroll
    for (int i = 0; i < 4; ++i) {
        int e = e0 + i;
        if (e < E) {
            int b = (int)((unsigned)darr[i] / (unsigned)BSZ);   // magic-mul const div
            int nl = darr[i] - b * BSZ;                          // 0..130
            recs[i] = (sarr[i] << 8) | nl;
            bks[i] = b;
            rr[i] = atomicAdd(&lhist[b], 1);   // rank fused with histogram
        } else bks[i] = -1;
    }
    __syncthreads();

    // 2-level wave scan of lhist (inclusive)
    int own = lhist[t];
    int v = own;
#pragma unroll
    for (int off = 1; off < 64; off <<= 1) {
        int u = __shfl_up(v, off, 64);
        if (lane >= off) v += u;
    }
    if (lane == 63) wsum[wid] = v;
    __syncthreads();
    if (wid == 0) {
        int s = (lane < 16) ? wsum[lane] : 0;
#pragma unroll
        for (int off = 1; off < 16; off <<= 1) {
            int u = __shfl_up(s, off, 64);
            if (lane >= off) s += u;
        }
        if (lane < 16) wsum[lane] = s;
    }
    __syncthreads();
    int incl = v + (wid ? wsum[wid - 1] : 0);
    int ex = incl - own;
    // transposed descriptor write: startsT[b][tau]; row b=Bn carries tile totals
    if (t <= Bn) startsT[(size_t)t * T + blockIdx.x] = ex;
    if (t < Bn) lofs[t] = ex;
    __syncthreads();

    // staged LDS sort + fully coalesced 16B flush
#pragma unroll
    for (int i = 0; i < 4; ++i) {
        if (bks[i] >= 0) stage[lofs[bks[i]] + rr[i]] = recs[i];
    }
    __syncthreads();

    int4* dp = reinterpret_cast<int4*>(records + (size_t)tileStart);
    const int4* sp = reinterpret_cast<const int4*>(stage);
    dp[t] = sp[t];

    // grid-stride feat -> bf16 shadow (coalesced float4 -> ushort4)
    if (useH) {
        int total4 = (N * D) >> 2;
        for (int i = blockIdx.x * STHREADS + t; i < total4; i += gridDim.x * STHREADS) {
            float4 f = ((const float4*)feat)[i];
            ushort4 h;
            h.x = f2bf(f.x); h.y = f2bf(f.y); h.z = f2bf(f.z); h.w = f2bf(f.w);
            ((ushort4*)featH)[i] = h;
        }
    }
}

// ---------- Pass 2: stream edges (packed u64 LDS atomics), decode+repack,
//            register-tiled combine. 131-node buckets -> balanced grid. ----------
template <bool USEH>
__global__ __launch_bounds__(512) void bucket_final(
        const float* __restrict__ feat, const unsigned short* __restrict__ featH,
        const int* __restrict__ records, const int* __restrict__ startsT,
        const float* __restrict__ Wself, const float* __restrict__ Wneigh,
        const float* __restrict__ bias, float* __restrict__ out,
        int N, int T, int Bn) {
    __shared__ float ubuf[(PN + 1) * SF];                 // raw[CAP] then sfeat[132][36]
    __shared__ unsigned long long sacc8[((PN + 1) * SF) / 2];  // u64 atomics -> f32 stride SF
    __shared__ float sWs[D * WP];
    __shared__ float sWn[D * WP];
    __shared__ float sb[D];
    __shared__ int sdeg[PN + 1];
    __shared__ int tstart[TMAX];
    __shared__ int tbase[TMAX + 1];
    __shared__ int wsum2[8];

    int* raw = reinterpret_cast<int*>(ubuf);
    float* sfeatF = ubuf;                                // stride SF after parking
    float* saccF = reinterpret_cast<float*>(sacc8);      // stride SF after decode

    int b = blockIdx.x;
    int t = threadIdx.x;
    int lane = t & 63;
    int wid = t >> 6;

    // ---- issue self-feature loads early (f32, exact; live across stream phase) ----
    const int NSLOT = PN * 8;          // 1048 float4 slots
    float4 fr[3];
#pragma unroll
    for (int u = 0; u < 3; ++u) fr[u] = make_float4(0.f, 0.f, 0.f, 0.f);
#pragma unroll
    for (int u = 0; u < 3; ++u) {
        int idx = t + 512 * u;
        if (idx < NSLOT) {
            int n = b * BSZ + (idx >> 3);
            if (n < N) fr[u] = ((const float4*)feat)[(size_t)n * 8 + (idx & 7)];
        }
    }

    // ---- init: zero accumulators, load weights/bias ----
    for (int i = t; i < ((PN + 1) * SF) / 2; i += 512) sacc8[i] = 0ull;
    if (t <= PN) sdeg[t] = 0;
    for (int i = t; i < D * D; i += 512) {
        int r = i >> 5, c = i & 31;
        sWs[r * WP + c] = Wself[i];
        sWn[r * WP + c] = Wneigh[i];
    }
    if (t < D) sb[t] = bias[t];

    // ---- A: coalesced descriptor load + exclusive scan over T tiles ----
    int myc = 0;
    if (t < T) {
        int s0v = startsT[(size_t)b * T + t];
        int s1v = startsT[(size_t)(b + 1) * T + t];
        tstart[t] = s0v;
        myc = s1v - s0v;
    }
    int v = myc;
#pragma unroll
    for (int off = 1; off < 64; off <<= 1) {
        int u = __shfl_up(v, off, 64);
        if (lane >= off) v += u;
    }
    if (lane == 63) wsum2[wid] = v;
    __syncthreads();
    if (wid == 0) {
        int s = (lane < 8) ? wsum2[lane] : 0;
#pragma unroll
        for (int off = 1; off < 8; off <<= 1) {
            int u = __shfl_up(s, off, 64);
            if (lane >= off) s += u;
        }
        if (lane < 8) wsum2[lane] = s;
    }
    __syncthreads();
    int incl = v + (wid ? wsum2[wid - 1] : 0);
    if (t < T) tbase[t] = incl - myc;
    if (t == T - 1) tbase[T] = incl;
    __syncthreads();

    int m = min(tbase[T], CAP);

    // ---- B: stage records into raw[] (single scattered-read pass) ----
    int lane4 = t & 3, tg4 = t >> 2;   // 128 tile-groups, 4 lanes each
    for (int tau = tg4; tau < T; tau += 128) {
        int s = tstart[tau];
        int rb = tbase[tau];
        int c2 = tbase[tau + 1] - rb;
        const int* rp = records + (size_t)tau * TILE + s;
        for (int l = lane4; l < c2; l += 4) {
            int pos = rb + l;
            if (pos < CAP) raw[pos] = rp[l];
        }
    }
    __syncthreads();

    // ---- C: stream-gather. 8-lane teams, packed ds_add_u64 atomics ----
    int team = t >> 3;       // 64 teams
    int part = t & 7;        // slice of the feat row (4 columns)
    if (USEH) {
        for (int base = team; base < m; base += 64 * DEPTHH) {
            ushort4 hv[DEPTHH];
            int nl8[DEPTHH];
            bool ok[DEPTHH];
#pragma unroll
            for (int u = 0; u < DEPTHH; ++u) {
                int idx = base + 64 * u;
                ok[u] = idx < m;
                int rec = raw[ok[u] ? idx : 0];       // LDS broadcast across the team
                int s = rec >> 8;
                nl8[u] = rec & 255;
                hv[u] = *reinterpret_cast<const ushort4*>(
                    featH + (size_t)s * D + part * 4); // 8B/lane, 64B/record
            }
#pragma unroll
            for (int u = 0; u < DEPTHH; ++u) {
                if (ok[u]) {
                    unsigned long long* ac = &sacc8[nl8[u] * APL + part * 2];
                    unsigned a0 = enc(bf2f(hv[u].x));
                    unsigned a1 = enc(bf2f(hv[u].y));
                    unsigned a2 = enc(bf2f(hv[u].z));
                    unsigned a3 = enc(bf2f(hv[u].w));
                    atomicAdd(ac + 0, (unsigned long long)a0 | ((unsigned long long)a1 << 32));
                    atomicAdd(ac + 1, (unsigned long long)a2 | ((unsigned long long)a3 << 32));
                    if (part == 0) atomicAdd(&sdeg[nl8[u]], 1);
                }
            }
        }
    } else {
        for (int base = team; base < m; base += 64 * DEPTH) {
            float4 vv[DEPTH];
            int nl8[DEPTH];
            bool ok[DEPTH];
#pragma unroll
            for (int u = 0; u < DEPTH; ++u) {
                int idx = base + 64 * u;
                ok[u] = idx < m;
                int rec = raw[ok[u] ? idx : 0];
                int s = rec >> 8;
                nl8[u] = rec & 255;
                vv[u] = *reinterpret_cast<const float4*>(
                    feat + (size_t)s * D + part * 4);
            }
#pragma unroll
            for (int u = 0; u < DEPTH; ++u) {
                if (ok[u]) {
                    unsigned long long* ac = &sacc8[nl8[u] * APL + part * 2];
                    unsigned a0 = enc(vv[u].x);
                    unsigned a1 = enc(vv[u].y);
                    unsigned a2 = enc(vv[u].z);
                    unsigned a3 = enc(vv[u].w);
                    atomicAdd(ac + 0, (unsigned long long)a0 | ((unsigned long long)a1 << 32));
                    atomicAdd(ac + 1, (unsigned long long)a2 | ((unsigned long long)a3 << 32));
                    if (part == 0) atomicAdd(&sdeg[nl8[u]], 1);
                }
            }
        }
    }
    __syncthreads();

    // ---- D: decode u64 accumulators (u32 view, word idx = node*2*APL+col),
    //         subtract deg*bias exactly, write f32 at stride SF;
    //         park self-features in LDS (raw[] is dead) ----
    unsigned rv[9];
    const unsigned* sview = reinterpret_cast<const unsigned*>(sacc8);
#pragma unroll
    for (int r = 0; r < 9; ++r) {
        int i = t + 512 * r;               // PN*32 = 4192 logical elements
        if (i < PN * 32) rv[r] = sview[(i >> 5) * (2 * APL) + (i & 31)];
    }
    __syncthreads();
#pragma unroll
    for (int r = 0; r < 9; ++r) {
        int i = t + 512 * r;
        if (i < PN * 32) {
            int node = i >> 5, col = i & 31;
            int iv = (int)(rv[r] - (unsigned)sdeg[node] * DEGBIAS);  // exact bias removal
            saccF[node * SF + col] = (float)iv * FXINV2;
        }
    }
#pragma unroll
    for (int u = 0; u < 3; ++u) {
        int idx = t + 512 * u;
        if (idx < NSLOT)
            *reinterpret_cast<float4*>(&sfeatF[(idx >> 3) * SF + (idx & 7) * 4]) = fr[u];
    }
    __syncthreads();

    // ---- E: register-tiled combine, 4 nodes x 2 j per thread; pass 2 covers 128..130 ----
    int jp = t & 15;          // j pair: j0 = jp, j1 = jp + 16
    int nq = t >> 4;          // node quad 0..31
    int j0 = jp, j1 = jp + 16;
    float b0 = sb[j0], b1 = sb[j1];
    for (int p2 = 0; p2 < 2; ++p2) {
        int q0 = nq + 32 * p2;
        if (q0 * 4 >= PN) break;           // only quad 32 survives pass 2
        float accS[4][2], accN[4][2];
#pragma unroll
        for (int i = 0; i < 4; ++i) {
            accS[i][0] = 0.f; accS[i][1] = 0.f;
            accN[i][0] = 0.f; accN[i][1] = 0.f;
        }
        const float* fb = &sfeatF[(q0 * 4) * SF];
        const float* nb = &saccF[(q0 * 4) * SF];
#pragma unroll 1
        for (int kk = 0; kk < 8; ++kk) {
            float4 w0 = *reinterpret_cast<const float4*>(&sWs[j0 * WP + kk * 4]);
            float4 w1 = *reinterpret_cast<const float4*>(&sWs[j1 * WP + kk * 4]);
            float4 u0 = *reinterpret_cast<const float4*>(&sWn[j0 * WP + kk * 4]);
            float4 u1 = *reinterpret_cast<const float4*>(&sWn[j1 * WP + kk * 4]);
#pragma unroll
            for (int i = 0; i < 4; ++i) {
                float4 f4 = *reinterpret_cast<const float4*>(&fb[i * SF + kk * 4]);
                float4 n4 = *reinterpret_cast<const float4*>(&nb[i * SF + kk * 4]);
                accS[i][0] += f4.x * w0.x + f4.y * w0.y + f4.z * w0.z + f4.w * w0.w;
                accS[i][1] += f4.x * w1.x + f4.y * w1.y + f4.z * w1.z + f4.w * w1.w;
                accN[i][0] += n4.x * u0.x + n4.y * u0.y + n4.z * u0.z + n4.w * u0.w;
                accN[i][1] += n4.x * u1.x + n4.y * u1.y + n4.z * u1.z + n4.w * u1.w;
            }
        }
#pragma unroll
        for (int i = 0; i < 4; ++i) {
            int nl = q0 * 4 + i;
            int n = b * BSZ + nl;
            if (nl < PN && n < N) {
                float inv = 1.0f / (float)max(sdeg[nl], 1);
                out[(size_t)n * D + j0] = accS[i][0] + inv * accN[i][0] + b0;
                out[(size_t)n * D + j1] = accS[i][1] + inv * accN[i][1] + b1;
            }
        }
    }
}

extern "C" void kernel_launch(void* const* d_in, const int* in_sizes, int n_in,
                              void* d_out, int out_size, void* d_ws, size_t ws_size,
                              hipStream_t stream) {
    const float* feat   = (const float*)d_in[0];
    const float* Wself  = (const float*)d_in[1];
    const float* Wneigh = (const float*)d_in[2];
    const float* bnb    = (const float*)d_in[3];
    const int*   src    = (const int*)d_in[4];
    const int*   dst    = (const int*)d_in[5];

    int N = in_sizes[0] / D;            // 100000
    int E = in_sizes[4];                // 1600000
    int Bn = (N + BSZ - 1) / BSZ;       // 764 (balanced bucket grid)
    int T  = (E + TILE - 1) / TILE;     // 391 (<= TMAX)

    // Workspace: records[T*TILE] | startsT[(Bn+1)*T] | featH[N*D] (bf16, 64B-aligned)
    size_t recB = (size_t)T * TILE * sizeof(int);
    size_t stB  = (size_t)(Bn + 1) * T * sizeof(int);
    size_t fhOff = (recB + stB + 63) & ~(size_t)63;
    size_t fhB = (size_t)N * D * sizeof(unsigned short);
    int useH = (fhOff + fhB <= ws_size) ? 1 : 0;

    int* records = (int*)d_ws;
    int* startsT = (int*)((char*)d_ws + recB);
    unsigned short* featH = (unsigned short*)((char*)d_ws + fhOff);

    scatter_tiles<<<T, STHREADS, 0, stream>>>(src, dst, records, startsT,
                                              feat, featH, E, Bn, T, N, useH);
    if (useH)
        bucket_final<true><<<Bn, 512, 0, stream>>>(feat, featH, records, startsT,
                                                   Wself, Wneigh, bnb,
                                                   (float*)d_out, N, T, Bn);
    else
        bucket_final<false><<<Bn, 512, 0, stream>>>(feat, featH, records, startsT,
                                                    Wself, Wneigh, bnb,
                                                    (float*)d_out, N, T, Bn);
}